// Round 16
// baseline (262.769 us; speedup 1.0000x reference)
//
#include <hip/hip_runtime.h>
#include <hip/hip_bf16.h>
#include <stdint.h>

typedef __bf16 bf16_t;
typedef __bf16 bf16x8 __attribute__((ext_vector_type(8)));
typedef __bf16 bf16x2 __attribute__((ext_vector_type(2)));
typedef float  f32x4  __attribute__((ext_vector_type(4)));
typedef float  f32x16 __attribute__((ext_vector_type(16)));
typedef unsigned int u32;
typedef u32 u32x4 __attribute__((ext_vector_type(4)));

#define D_MODEL 1024
#define NHEAD   16
#define DEPTH   64
#define BATCH   4
#define SEQ     2048
#define MROWS   (BATCH*SEQ)

// 0.125 (1/sqrt(64)) * log2(e): folded into the Q-projection GEMM epilogue.
#define SC 0.18033688011112042f

__device__ __forceinline__ void gload16(const void* g, void* l) {
    __builtin_amdgcn_global_load_lds(
        (__attribute__((address_space(1))) void*)(uintptr_t)g,
        (__attribute__((address_space(3))) void*)l,
        16, 0, 0);
}

__device__ __forceinline__ u32 pk2(float a, float b) {
    bf16x2 t; t[0] = (bf16_t)a; t[1] = (bf16_t)b;
    return __builtin_bit_cast(u32, t);
}

// ---- 4 weight converts in one launch (blockIdx.y selects tensor) ----
__global__ __launch_bounds__(256) void cvtw_kernel(const float* __restrict__ s0, bf16_t* __restrict__ d0,
                                                   const float* __restrict__ s1, bf16_t* __restrict__ d1,
                                                   const float* __restrict__ s2, bf16_t* __restrict__ d2,
                                                   const float* __restrict__ s3, bf16_t* __restrict__ d3,
                                                   int n8) {
    int i = blockIdx.x * 256 + threadIdx.x;
    if (i >= n8) return;
    const float* src; bf16_t* dst;
    switch (blockIdx.y) {
        case 0: src = s0; dst = d0; break;
        case 1: src = s1; dst = d1; break;
        case 2: src = s2; dst = d2; break;
        default: src = s3; dst = d3; break;
    }
    const float4* s4 = (const float4*)src;
    float4 a = s4[2*(size_t)i], b = s4[2*(size_t)i + 1];
    bf16x8 o;
    o[0] = (bf16_t)a.x; o[1] = (bf16_t)a.y; o[2] = (bf16_t)a.z; o[3] = (bf16_t)a.w;
    o[4] = (bf16_t)b.x; o[5] = (bf16_t)b.y; o[6] = (bf16_t)b.z; o[7] = (bf16_t)b.w;
    *(bf16x8*)(dst + 8*(size_t)i) = o;
}

// ---------------- GEMM: C = (A[M,K] * Bw[N,K]^T + bias) * scale ----------------
// 1-D grid, XCD-aligned columns: bn = (bid&7)*128 -> each XCD owns one B-panel.
// Single-buffered K-loop (r15's dbuf was neutral; r14 structure restored).
// AF32=1: A is f32 in GLOBAL, staged RAW via global_load_lds (fully async — r12's
// reg-staging failure mode absent) into a 32KB f32 pane; f32->bf16 conversion
// happens at fragment-load (2x ds_read_b128 + 4 cvt_pk, in the compute phase).
// Swizzle for 4B elems: src chunk c^((r&7)<<1), read byte^((r&7)<<5) (<=2-way, free).
// MODE 0: f32 C. MODE 1: bf16 C. MODE 2: bf16 C TRANSPOSED to Vt[b*16+h][d][s'].
template<int MODE, int AF32>
__global__ __launch_bounds__(256) void gemm_bt(const void* __restrict__ Av,
                                               const bf16_t* __restrict__ Bw,
                                               const float* __restrict__ bias,
                                               bf16_t* __restrict__ Cb,
                                               float* __restrict__ Cf,
                                               int M, int N, int K, float scale) {
    constexpr int ABYTES = AF32 ? 128*64*4 : 128*64*2;
    __shared__ __align__(16) char Smem[ABYTES + 128*64*2];   // A pane | B pane
    bf16_t* Bs = (bf16_t*)(Smem + ABYTES);
    const int tid  = threadIdx.x;
    const int wave = tid >> 6, lane = tid & 63;
    const int lr = lane & 15, lk = (lane >> 4) * 8;
    const int bm = (blockIdx.x >> 3) * 128, bn = (blockIdx.x & 7) * 128;
    const int wr = (wave >> 1) * 64, wc = (wave & 1) * 64;

    f32x4 acc[4][4] = {};

    for (int kt = 0; kt < K; kt += 64) {
        if (AF32) {
            const float* A32 = (const float*)Av;
#pragma unroll
            for (int p = 0; p < 8; ++p) {
                int chunk = p*256 + tid;          // 0..2047 (16B = 4 f32)
                int r = chunk >> 4, c = chunk & 15;
                int cs = (c ^ ((r & 7) << 1)) * 4;    // pre-swizzled f32 col
                gload16(A32 + (size_t)(bm + r)*K + kt + cs,
                        (float*)Smem + (size_t)chunk*4);
            }
        } else {
            const bf16_t* A16 = (const bf16_t*)Av;
#pragma unroll
            for (int p = 0; p < 4; ++p) {
                int chunk = p*256 + tid;
                int r = chunk >> 3;
                int cs = ((chunk & 7) ^ (r & 7)) * 8;
                gload16(A16 + (size_t)(bm + r)*K + kt + cs,
                        (bf16_t*)Smem + (size_t)chunk*8);
            }
        }
#pragma unroll
        for (int p = 0; p < 4; ++p) {
            int chunk = p*256 + tid;
            int r = chunk >> 3;
            int cs = ((chunk & 7) ^ (r & 7)) * 8;
            gload16(Bw + (size_t)(bn + r)*K + kt + cs, Bs + (size_t)chunk*8);
        }
        __syncthreads();
        const char* AsB = (const char*)Smem;
        const char* BsB = (const char*)Bs;
#pragma unroll
        for (int ks = 0; ks < 2; ++ks) {
            int kb = (ks*32 + lk) * 2;
            bf16x8 af[4], bfv[4];
#pragma unroll
            for (int mi = 0; mi < 4; ++mi) {
                int row = wr + mi*16 + lr;
                if (AF32) {
                    int swz = (row*256 + (ks*32 + lk)*4) ^ ((row & 7) << 5);
                    f32x4 lo = *(const f32x4*)(AsB + swz);
                    f32x4 hi = *(const f32x4*)(AsB + swz + 16);
                    u32x4 w;
                    w[0] = pk2(lo[0], lo[1]); w[1] = pk2(lo[2], lo[3]);
                    w[2] = pk2(hi[0], hi[1]); w[3] = pk2(hi[2], hi[3]);
                    af[mi] = __builtin_bit_cast(bf16x8, w);
                } else {
                    af[mi] = *(const bf16x8*)(AsB + ((row*128 + kb) ^ ((row & 7) << 4)));
                }
            }
#pragma unroll
            for (int ni = 0; ni < 4; ++ni) {
                int row = wc + ni*16 + lr;
                bfv[ni] = *(const bf16x8*)(BsB + ((row*128 + kb) ^ ((row & 7) << 4)));
            }
            __builtin_amdgcn_s_setprio(1);
#pragma unroll
            for (int mi = 0; mi < 4; ++mi)
#pragma unroll
                for (int ni = 0; ni < 4; ++ni)
                    acc[mi][ni] = __builtin_amdgcn_mfma_f32_16x16x32_bf16(
                        af[mi], bfv[ni], acc[mi][ni], 0, 0, 0);
            __builtin_amdgcn_s_setprio(0);
        }
        __syncthreads();
    }

    if (MODE != 2) {
#pragma unroll
        for (int ni = 0; ni < 4; ++ni) {
            int col = bn + wc + ni*16 + lr;
            float bv = bias[col];
#pragma unroll
            for (int mi = 0; mi < 4; ++mi) {
#pragma unroll
                for (int j = 0; j < 4; ++j) {
                    int row = bm + wr + mi*16 + (lane >> 4)*4 + j;
                    float vv = (acc[mi][ni][j] + bv) * scale;
                    if (MODE == 1) Cb[(size_t)row*N + col] = (bf16_t)vv;
                    else           Cf[(size_t)row*N + col] = vv;
                }
            }
        }
    } else {
        // ---- transposed V epilogue: acc -> LDS[col][s'] -> coalesced Vt stores
        char* TB = (char*)Smem;           // K-loop ended with syncthreads: safe
#pragma unroll
        for (int ni = 0; ni < 4; ++ni) {
            int col = wc + ni*16 + lr;    // local col 0..127
            int swz = (col & 7) << 4;
            float bv = bias[bn + col];
#pragma unroll
            for (int mi = 0; mi < 4; ++mi)
#pragma unroll
                for (int j = 0; j < 4; ++j) {
                    int row = wr + mi*16 + (lane >> 4)*4 + j;   // local s 0..127
                    int sp  = (row & ~12) | ((row & 4) << 1) | ((row & 8) >> 1);
                    float vv = (acc[mi][ni][j] + bv) * scale;
                    *(bf16_t*)(TB + ((col*256 + sp*2) ^ swz)) = (bf16_t)vv;
                }
        }
        __syncthreads();
        const int b = bm >> 11, sl = bm & 2047;
#pragma unroll
        for (int p = 0; p < 8; ++p) {
            int id = p*256 + tid;
            int col = id >> 4, sg = id & 15;
            bf16x8 v8 = *(const bf16x8*)(TB + ((col*256 + sg*16) ^ ((col & 7) << 4)));
            int gc = bn + col;
            int bh = b*16 + (gc >> 6), d = gc & 63;
            *(bf16x8*)&Cb[((size_t)bh*DEPTH + d)*SEQ + sl + sg*8] = v8;
        }
    }
}

// ---------------- Flash attention ----------------
// 256 q/block (2 q-subtiles of 128), 4 waves. 64-key tiles, triple-buffered K,V^T
// via global_load_lds with COUNTED vmcnt — staging/mask/boundary amortized over 2x
// MFMA work, 2 independent q-streams of in-wave ILP. Fixed-base softmax (m=0, exact;
// scale pre-folded into Q). Mask rides the MFMA pipe (rank-1 accumulator init);
// l-sum on VALU (independent adds — MFMA version serialized, r10).
// __launch_bounds__(256,2): (256,3) forced accumulator spill (r13).
__global__ __launch_bounds__(256, 2) void attn_kernel(const bf16_t* __restrict__ Qp,
                                                      const bf16_t* __restrict__ Kp,
                                                      const bf16_t* __restrict__ Vt,
                                                      const int* __restrict__ mask,
                                                      bf16_t* __restrict__ AO) {
    __shared__ bf16_t Ks[3][64*64];   // [key][d], XOR-swizzled via pre-swizzled src
    __shared__ bf16_t Vs[3][64*64];   // [d][key'], XOR-swizzled
    __shared__ bf16_t mbias[SEQ];     // additive mask bias (0 or -1e30), bf16

    const int tid  = threadIdx.x;
    const int wave = tid >> 6, lane = tid & 63;
    const int lr5 = lane & 31;
    const int hi  = lane >> 5;

    // XCD-aware work remap over grid (8,16,4): xcd = flat&7 owns 8 bh pairs x 8 q-blocks.
    const int flat = blockIdx.x + 8*blockIdx.y + 128*blockIdx.z;
    const int xcd = flat & 7, slot = flat >> 3;        // slot 0..63
    const int bh = xcd + 8*(slot >> 3);
    const int b = bh >> 4, h = bh & 15;
    const int q0 = (slot & 7) * 256;

    const size_t base  = (size_t)b * SEQ * D_MODEL + (size_t)h * DEPTH;
    const size_t vbase = (size_t)bh * DEPTH * SEQ;

    // Q fragments for both q-subtiles (pre-scaled by SC in the Q-projection GEMM)
    bf16x8 qf[2][4];
#pragma unroll
    for (int qs = 0; qs < 2; ++qs)
#pragma unroll
        for (int dc = 0; dc < 4; ++dc)
            qf[qs][dc] = *(const bf16x8*)&Qp[base +
                (size_t)(q0 + qs*128 + wave*32 + lr5)*D_MODEL + dc*16 + hi*8];

    // ones B-fragment for the rank-1 mask update: B[q][k]=1 at k=0 only
    u32x4 onew = {};
    onew[0] = hi ? 0u : 0x3F80u;
    const bf16x8 qone = __builtin_bit_cast(bf16x8, onew);

    // ---- stage bf16 mask bias row once (all 256 threads, 8 keys each)
    {
        const int4* mp = (const int4*)&mask[(size_t)b*SEQ + tid*8];
        int4 m0 = mp[0], m1 = mp[1];
        bf16x8 mm;
        mm[0] = (m0.x == 0) ? (bf16_t)(-1e30f) : (bf16_t)0.0f;
        mm[1] = (m0.y == 0) ? (bf16_t)(-1e30f) : (bf16_t)0.0f;
        mm[2] = (m0.z == 0) ? (bf16_t)(-1e30f) : (bf16_t)0.0f;
        mm[3] = (m0.w == 0) ? (bf16_t)(-1e30f) : (bf16_t)0.0f;
        mm[4] = (m1.x == 0) ? (bf16_t)(-1e30f) : (bf16_t)0.0f;
        mm[5] = (m1.y == 0) ? (bf16_t)(-1e30f) : (bf16_t)0.0f;
        mm[6] = (m1.z == 0) ? (bf16_t)(-1e30f) : (bf16_t)0.0f;
        mm[7] = (m1.w == 0) ? (bf16_t)(-1e30f) : (bf16_t)0.0f;
        *(bf16x8*)&mbias[tid*8] = mm;
    }

    auto stage = [&](int t, int buf) {
#pragma unroll
        for (int p = 0; p < 2; ++p) {
            int chunk = p*256 + tid; int r = chunk >> 3;
            int cs = ((chunk & 7) ^ (r & 7)) * 8;
            gload16(Kp + base + (size_t)(t*64 + r)*D_MODEL + cs,
                    (bf16_t*)Ks[buf] + (size_t)chunk*8);
            gload16(Vt + vbase + (size_t)r*SEQ + t*64 + cs,
                    (bf16_t*)Vs[buf] + (size_t)chunk*8);
        }
    };

    f32x16 oA0 = {}, oA1 = {};        // q-sub 0: O^T accumulators (d 0..31 / 32..63)
    f32x16 oB0 = {}, oB1 = {};        // q-sub 1
    float lA = 0.f, lB = 0.f;         // own-half softmax denominators

    // ---- prologue: issue tiles 0,1,2; counted wait (qf+mask+tile0 retired)
    stage(0, 0); stage(1, 1); stage(2, 2);
    asm volatile("s_waitcnt vmcnt(8) lgkmcnt(0)");
    __builtin_amdgcn_s_barrier();

    int cb = 0;                        // current buffer = t % 3
    for (int t = 0; t < SEQ/64; ++t) {
        // ---- mask A-fragments (shared by both q-subs)
        u32 mw0 = (u32)__builtin_bit_cast(unsigned short, mbias[t*64 + lr5]);
        u32 mw1 = (u32)__builtin_bit_cast(unsigned short, mbias[t*64 + 32 + lr5]);
        if (hi) { mw0 = 0; mw1 = 0; }
        u32x4 mv0 = {}, mv1 = {};
        mv0[0] = mw0; mv1[0] = mw1;
        bf16x8 afm0 = __builtin_bit_cast(bf16x8, mv0);
        bf16x8 afm1 = __builtin_bit_cast(bf16x8, mv1);

        const char* KsB = (const char*)Ks[cb];
        const char* VsB = (const char*)Vs[cb];

#pragma unroll
        for (int qs = 0; qs < 2; ++qs) {
            // ---- QK(t,qs): S^T[key][q], accumulator initialized with rank-1 mask
            const f32x16 zz = {};
            f32x16 s0, s1;
            __builtin_amdgcn_s_setprio(1);
            s0 = __builtin_amdgcn_mfma_f32_32x32x16_bf16(afm0, qone, zz, 0, 0, 0);
            s1 = __builtin_amdgcn_mfma_f32_32x32x16_bf16(afm1, qone, zz, 0, 0, 0);
#pragma unroll
            for (int dc = 0; dc < 4; ++dc) {
                int colb = dc*32 + hi*16;
                int row0 = lr5, row1 = 32 + lr5;
                bf16x8 kf0 = *(const bf16x8*)(KsB + ((row0*128 + colb) ^ ((row0 & 7) << 4)));
                bf16x8 kf1 = *(const bf16x8*)(KsB + ((row1*128 + colb) ^ ((row1 & 7) << 4)));
                s0 = __builtin_amdgcn_mfma_f32_32x32x16_bf16(kf0, qf[qs][dc], s0, 0, 0, 0);
                s1 = __builtin_amdgcn_mfma_f32_32x32x16_bf16(kf1, qf[qs][dc], s1, 0, 0, 0);
            }
            __builtin_amdgcn_s_setprio(0);

            // ---- per kt-half: exp2 -> sum -> pack -> PV (pv[16] live at a time)
            float lsum = 0.f;
#pragma unroll
            for (int kt = 0; kt < 2; ++kt) {
                const f32x16& sh = kt ? s1 : s0;
                float pv[16];
#pragma unroll
                for (int r = 0; r < 16; ++r) pv[r] = __builtin_exp2f(sh[r]);
                float su0 = 0.f, su1 = 0.f, su2 = 0.f, su3 = 0.f;
#pragma unroll
                for (int r = 0; r < 16; r += 4) {
                    su0 += pv[r]; su1 += pv[r+1]; su2 += pv[r+2]; su3 += pv[r+3];
                }
                lsum += (su0 + su1) + (su2 + su3);
#pragma unroll
                for (int c = 0; c < 2; ++c) {
                    u32x4 fwv;
#pragma unroll
                    for (int i = 0; i < 4; ++i)
                        fwv[i] = pk2(pv[c*8 + 2*i], pv[c*8 + 2*i + 1]);
                    bf16x8 pfrag = __builtin_bit_cast(bf16x8, fwv);
                    int colb = kt*64 + c*32 + hi*16;
                    int row0 = lr5, row1 = 32 + lr5;
                    bf16x8 vf0 = *(const bf16x8*)(VsB + ((row0*128 + colb) ^ ((row0 & 7) << 4)));
                    bf16x8 vf1 = *(const bf16x8*)(VsB + ((row1*128 + colb) ^ ((row1 & 7) << 4)));
                    __builtin_amdgcn_s_setprio(1);
                    if (qs == 0) {
                        oA0 = __builtin_amdgcn_mfma_f32_32x32x16_bf16(vf0, pfrag, oA0, 0, 0, 0);
                        oA1 = __builtin_amdgcn_mfma_f32_32x32x16_bf16(vf1, pfrag, oA1, 0, 0, 0);
                    } else {
                        oB0 = __builtin_amdgcn_mfma_f32_32x32x16_bf16(vf0, pfrag, oB0, 0, 0, 0);
                        oB1 = __builtin_amdgcn_mfma_f32_32x32x16_bf16(vf1, pfrag, oB1, 0, 0, 0);
                    }
                    __builtin_amdgcn_s_setprio(0);
                }
            }
            if (qs == 0) lA += lsum; else lB += lsum;
        }

        // ---- boundary: counted wait — stage(t+1) retired, stage(t+2) stays in flight
        asm volatile("s_waitcnt vmcnt(4) lgkmcnt(0)");
        __builtin_amdgcn_s_barrier();
        if (t + 3 < SEQ/64) stage(t + 3, cb);   // buffer (t+3)%3 == t%3 == cb
        ++cb; if (cb == 3) cb = 0;
    }

    // ---- epilogue per q-sub: cross-half l; O^T/l; transpose through LDS; store
    char* TrB = (char*)Ks;            // 16KB reuse (final barrier above protects)
    const int qloc = wave*32 + lr5;
#pragma unroll
    for (int qs = 0; qs < 2; ++qs) {
        if (qs) __syncthreads();      // protect TrB reuse between q-subs
        float lr_ = (qs == 0) ? lA : lB;
        float l_tot = lr_ + __shfl_xor(lr_, 32);
        float inv = 1.f / l_tot;
#pragma unroll
        for (int mt = 0; mt < 2; ++mt)
#pragma unroll
            for (int r = 0; r < 16; ++r) {
                int d = mt*32 + (r & 3) + 8*(r >> 2) + 4*hi;
                float val = (qs == 0 ? (mt ? oA1[r] : oA0[r])
                                     : (mt ? oB1[r] : oB0[r])) * inv;
                *(bf16_t*)(TrB + (qloc*128 + ((d*2) ^ ((qloc & 7) << 4)))) = (bf16_t)val;
            }
        __syncthreads();
#pragma unroll
        for (int p = 0; p < 4; ++p) {
            int id = p*256 + tid;
            int row = id >> 3, g = id & 7;
            bf16x8 v8 = *(const bf16x8*)(TrB + (row*128 + ((g*16) ^ ((row & 7) << 4))));
            *(bf16x8*)&AO[base + (size_t)(q0 + qs*128 + row)*D_MODEL + g*8] = v8;
        }
    }
}

extern "C" void kernel_launch(void* const* d_in, const int* in_sizes, int n_in,
                              void* d_out, int out_size, void* d_ws, size_t ws_size,
                              hipStream_t stream) {
    (void)in_sizes; (void)n_in; (void)out_size; (void)ws_size;
    const float* q    = (const float*)d_in[0];
    const float* k    = (const float*)d_in[1];
    const float* v    = (const float*)d_in[2];
    const int*   mask = (const int*)d_in[3];
    const float* wq_w = (const float*)d_in[4];
    const float* wq_b = (const float*)d_in[5];
    const float* wk_w = (const float*)d_in[6];
    const float* wk_b = (const float*)d_in[7];
    const float* wv_w = (const float*)d_in[8];
    const float* wv_b = (const float*)d_in[9];
    const float* wo_w = (const float*)d_in[10];
    const float* wo_b = (const float*)d_in[11];
    float* out = (float*)d_out;

    const size_t ACT = (size_t)MROWS * D_MODEL;
    const size_t WSZ = (size_t)D_MODEL * D_MODEL;
    bf16_t* Qp = (bf16_t*)d_ws;
    bf16_t* Kp = Qp + ACT;
    bf16_t* Vt = Kp + ACT;            // V written DIRECTLY transposed by gemm_bt<2,1>
    bf16_t* AO = Vt + ACT;
    bf16_t* Wq = AO + ACT;
    bf16_t* Wk = Wq + WSZ;
    bf16_t* Wv = Wk + WSZ;
    bf16_t* Wo = Wv + WSZ;

    const int wn8 = (int)(WSZ/8);
    cvtw_kernel<<<dim3(wn8/256, 4), dim3(256), 0, stream>>>(wq_w, Wq, wk_w, Wk, wv_w, Wv, wo_w, Wo, wn8);

    const int ggrid = (MROWS/128) * (D_MODEL/128);   // 512, 1-D XCD-aligned
    // QKV projections read f32 inputs directly (async f32 staging + fragment-time cvt)
    gemm_bt<1,1><<<ggrid, dim3(256), 0, stream>>>(q, Wq, wq_b, Qp, nullptr, MROWS, D_MODEL, D_MODEL, SC);
    gemm_bt<1,1><<<ggrid, dim3(256), 0, stream>>>(k, Wk, wk_b, Kp, nullptr, MROWS, D_MODEL, D_MODEL, 1.f);
    gemm_bt<2,1><<<ggrid, dim3(256), 0, stream>>>(v, Wv, wv_b, Vt, nullptr, MROWS, D_MODEL, D_MODEL, 1.f);

    attn_kernel<<<dim3(SEQ/256, NHEAD, BATCH), dim3(256), 0, stream>>>(Qp, Kp, Vt, mask, AO);

    gemm_bt<0,0><<<ggrid, dim3(256), 0, stream>>>(AO, Wo, wo_b, nullptr, out, MROWS, D_MODEL, D_MODEL, 1.f);
}

// Round 17
// 228.930 us; speedup vs baseline: 1.1478x; 1.1478x over previous
//
#include <hip/hip_runtime.h>
#include <hip/hip_bf16.h>
#include <stdint.h>

typedef __bf16 bf16_t;
typedef __bf16 bf16x8 __attribute__((ext_vector_type(8)));
typedef __bf16 bf16x2 __attribute__((ext_vector_type(2)));
typedef float  f32x4  __attribute__((ext_vector_type(4)));
typedef float  f32x16 __attribute__((ext_vector_type(16)));
typedef unsigned int u32;
typedef u32 u32x4 __attribute__((ext_vector_type(4)));

#define D_MODEL 1024
#define NHEAD   16
#define DEPTH   64
#define BATCH   4
#define SEQ     2048
#define MROWS   (BATCH*SEQ)

// 0.125 (1/sqrt(64)) * log2(e): folded into the Q-projection GEMM epilogue.
#define SC 0.18033688011112042f

// ======================= PROVEN-BEST CONFIGURATION (r14: 229.0 us) ============
// Closed lines (do not reintroduce):
//  - r12/r16: any f32->bf16 convert fused into GEMM A-staging (reg-staged OR
//    raw-f32-LDS + fragment-time cvt) loses 30-42us vs the standalone cvt3 pass.
//  - r15: GEMM double-buffer + counted vmcnt is neutral-to-negative (implicit
//    2-block/CU TLP already hides the staging drain; +1 barrier +LDS costs ~5us).
//  - r10: l-sum as MFMA (serialized accumulator chain). r7: mask as bf16 cvt in
//    VALU epilogue (register cliff). r13: 2-q-tile attn under (256,3) (spill).
// ==============================================================================

__device__ __forceinline__ void gload16(const void* g, void* l) {
    __builtin_amdgcn_global_load_lds(
        (__attribute__((address_space(1))) void*)(uintptr_t)g,
        (__attribute__((address_space(3))) void*)l,
        16, 0, 0);
}

__device__ __forceinline__ u32 pk2(float a, float b) {
    bf16x2 t; t[0] = (bf16_t)a; t[1] = (bf16_t)b;
    return __builtin_bit_cast(u32, t);
}

// ---- q/k/v converts in one launch (blockIdx.y selects tensor) ----
__global__ __launch_bounds__(256) void cvt3_kernel(const float* __restrict__ s0, bf16_t* __restrict__ d0,
                                                   const float* __restrict__ s1, bf16_t* __restrict__ d1,
                                                   const float* __restrict__ s2, bf16_t* __restrict__ d2,
                                                   int n8) {
    int i = blockIdx.x * 256 + threadIdx.x;
    if (i >= n8) return;
    const float* src; bf16_t* dst;
    switch (blockIdx.y) {
        case 0: src = s0; dst = d0; break;
        case 1: src = s1; dst = d1; break;
        default: src = s2; dst = d2; break;
    }
    const float4* s4 = (const float4*)src;
    float4 a = s4[2*(size_t)i], b = s4[2*(size_t)i + 1];
    bf16x8 o;
    o[0] = (bf16_t)a.x; o[1] = (bf16_t)a.y; o[2] = (bf16_t)a.z; o[3] = (bf16_t)a.w;
    o[4] = (bf16_t)b.x; o[5] = (bf16_t)b.y; o[6] = (bf16_t)b.z; o[7] = (bf16_t)b.w;
    *(bf16x8*)(dst + 8*(size_t)i) = o;
}

// ---- 4 weight converts in one launch (blockIdx.y selects tensor) ----
__global__ __launch_bounds__(256) void cvtw_kernel(const float* __restrict__ s0, bf16_t* __restrict__ d0,
                                                   const float* __restrict__ s1, bf16_t* __restrict__ d1,
                                                   const float* __restrict__ s2, bf16_t* __restrict__ d2,
                                                   const float* __restrict__ s3, bf16_t* __restrict__ d3,
                                                   int n8) {
    int i = blockIdx.x * 256 + threadIdx.x;
    if (i >= n8) return;
    const float* src; bf16_t* dst;
    switch (blockIdx.y) {
        case 0: src = s0; dst = d0; break;
        case 1: src = s1; dst = d1; break;
        case 2: src = s2; dst = d2; break;
        default: src = s3; dst = d3; break;
    }
    const float4* s4 = (const float4*)src;
    float4 a = s4[2*(size_t)i], b = s4[2*(size_t)i + 1];
    bf16x8 o;
    o[0] = (bf16_t)a.x; o[1] = (bf16_t)a.y; o[2] = (bf16_t)a.z; o[3] = (bf16_t)a.w;
    o[4] = (bf16_t)b.x; o[5] = (bf16_t)b.y; o[6] = (bf16_t)b.z; o[7] = (bf16_t)b.w;
    *(bf16x8*)(dst + 8*(size_t)i) = o;
}

// ---------------- GEMM: C = (A[M,K] * Bw[N,K]^T + bias) * scale ----------------
// 1-D grid, XCD-aligned columns: bn = (bid&7)*128 -> each XCD owns one B-panel
// (256KB, L2-resident). Single-buffered bf16 A/B via global_load_lds.
// MODE 0: f32 C. MODE 1: bf16 C. MODE 2: bf16 C TRANSPOSED to Vt[b*16+h][d][s']
// (s' = key-bit-swap layout) via LDS — fuses the V transpose for attention.
template<int MODE>
__global__ __launch_bounds__(256) void gemm_bt(const bf16_t* __restrict__ A,
                                               const bf16_t* __restrict__ Bw,
                                               const float* __restrict__ bias,
                                               bf16_t* __restrict__ Cb,
                                               float* __restrict__ Cf,
                                               int M, int N, int K, float scale) {
    __shared__ bf16_t Smem[2*128*64];     // As | Bs; reused as 128x128 transpose buf
    bf16_t* As = Smem;
    bf16_t* Bs = Smem + 128*64;
    const int tid  = threadIdx.x;
    const int wave = tid >> 6, lane = tid & 63;
    const int lr = lane & 15, lk = (lane >> 4) * 8;
    const int bm = (blockIdx.x >> 3) * 128, bn = (blockIdx.x & 7) * 128;
    const int wr = (wave >> 1) * 64, wc = (wave & 1) * 64;

    f32x4 acc[4][4] = {};

    for (int kt = 0; kt < K; kt += 64) {
#pragma unroll
        for (int p = 0; p < 4; ++p) {
            int chunk = p*256 + tid;
            int r  = chunk >> 3;
            int cs = ((chunk & 7) ^ (r & 7)) * 8;
            gload16(A  + (size_t)(bm + r)*K + kt + cs, As + (size_t)chunk*8);
            gload16(Bw + (size_t)(bn + r)*K + kt + cs, Bs + (size_t)chunk*8);
        }
        __syncthreads();
        const char* AsB = (const char*)As;
        const char* BsB = (const char*)Bs;
#pragma unroll
        for (int ks = 0; ks < 2; ++ks) {
            int kb = (ks*32 + lk) * 2;
            bf16x8 af[4], bfv[4];
#pragma unroll
            for (int mi = 0; mi < 4; ++mi) {
                int row = wr + mi*16 + lr;
                af[mi] = *(const bf16x8*)(AsB + ((row*128 + kb) ^ ((row & 7) << 4)));
            }
#pragma unroll
            for (int ni = 0; ni < 4; ++ni) {
                int row = wc + ni*16 + lr;
                bfv[ni] = *(const bf16x8*)(BsB + ((row*128 + kb) ^ ((row & 7) << 4)));
            }
            __builtin_amdgcn_s_setprio(1);
#pragma unroll
            for (int mi = 0; mi < 4; ++mi)
#pragma unroll
                for (int ni = 0; ni < 4; ++ni)
                    acc[mi][ni] = __builtin_amdgcn_mfma_f32_16x16x32_bf16(
                        af[mi], bfv[ni], acc[mi][ni], 0, 0, 0);
            __builtin_amdgcn_s_setprio(0);
        }
        __syncthreads();
    }

    if (MODE != 2) {
#pragma unroll
        for (int ni = 0; ni < 4; ++ni) {
            int col = bn + wc + ni*16 + lr;
            float bv = bias[col];
#pragma unroll
            for (int mi = 0; mi < 4; ++mi) {
#pragma unroll
                for (int j = 0; j < 4; ++j) {
                    int row = bm + wr + mi*16 + (lane >> 4)*4 + j;
                    float vv = (acc[mi][ni][j] + bv) * scale;
                    if (MODE == 1) Cb[(size_t)row*N + col] = (bf16_t)vv;
                    else           Cf[(size_t)row*N + col] = vv;
                }
            }
        }
    } else {
        // ---- transposed V epilogue: acc -> LDS[col][s'] -> coalesced Vt stores
        char* TB = (char*)Smem;           // K-loop ended with syncthreads: safe
#pragma unroll
        for (int ni = 0; ni < 4; ++ni) {
            int col = wc + ni*16 + lr;    // local col 0..127
            int swz = (col & 7) << 4;
            float bv = bias[bn + col];
#pragma unroll
            for (int mi = 0; mi < 4; ++mi)
#pragma unroll
                for (int j = 0; j < 4; ++j) {
                    int row = wr + mi*16 + (lane >> 4)*4 + j;   // local s 0..127
                    int sp  = (row & ~12) | ((row & 4) << 1) | ((row & 8) >> 1);
                    float vv = (acc[mi][ni][j] + bv) * scale;
                    *(bf16_t*)(TB + ((col*256 + sp*2) ^ swz)) = (bf16_t)vv;
                }
        }
        __syncthreads();
        const int b = bm >> 11, sl = bm & 2047;
#pragma unroll
        for (int p = 0; p < 8; ++p) {
            int id = p*256 + tid;
            int col = id >> 4, sg = id & 15;
            bf16x8 v8 = *(const bf16x8*)(TB + ((col*256 + sg*16) ^ ((col & 7) << 4)));
            int gc = bn + col;
            int bh = b*16 + (gc >> 6), d = gc & 63;
            *(bf16x8*)&Cb[((size_t)bh*DEPTH + d)*SEQ + sl + sg*8] = v8;
        }
    }
}

// ---------------- Flash attention ----------------
// 256 q/block (2 q-subtiles of 128), 4 waves. 64-key tiles, triple-buffered K,V^T
// via global_load_lds with COUNTED vmcnt — staging/mask/boundary amortized over 2x
// MFMA work, 2 independent q-streams of in-wave ILP. Fixed-base softmax (m=0, exact
// by shift-invariance; scale pre-folded into Q). Mask rides the MFMA pipe (rank-1
// accumulator init); l-sum on VALU (independent adds — MFMA version serialized, r10).
// __launch_bounds__(256,2): (256,3) forced accumulator spill (r13).
__global__ __launch_bounds__(256, 2) void attn_kernel(const bf16_t* __restrict__ Qp,
                                                      const bf16_t* __restrict__ Kp,
                                                      const bf16_t* __restrict__ Vt,
                                                      const int* __restrict__ mask,
                                                      bf16_t* __restrict__ AO) {
    __shared__ bf16_t Ks[3][64*64];   // [key][d], XOR-swizzled via pre-swizzled src
    __shared__ bf16_t Vs[3][64*64];   // [d][key'], XOR-swizzled
    __shared__ bf16_t mbias[SEQ];     // additive mask bias (0 or -1e30), bf16

    const int tid  = threadIdx.x;
    const int wave = tid >> 6, lane = tid & 63;
    const int lr5 = lane & 31;
    const int hi  = lane >> 5;

    // XCD-aware work remap over grid (8,16,4): xcd = flat&7 owns 8 bh pairs x 8 q-blocks.
    const int flat = blockIdx.x + 8*blockIdx.y + 128*blockIdx.z;
    const int xcd = flat & 7, slot = flat >> 3;        // slot 0..63
    const int bh = xcd + 8*(slot >> 3);
    const int b = bh >> 4, h = bh & 15;
    const int q0 = (slot & 7) * 256;

    const size_t base  = (size_t)b * SEQ * D_MODEL + (size_t)h * DEPTH;
    const size_t vbase = (size_t)bh * DEPTH * SEQ;

    // Q fragments for both q-subtiles (pre-scaled by SC in the Q-projection GEMM)
    bf16x8 qf[2][4];
#pragma unroll
    for (int qs = 0; qs < 2; ++qs)
#pragma unroll
        for (int dc = 0; dc < 4; ++dc)
            qf[qs][dc] = *(const bf16x8*)&Qp[base +
                (size_t)(q0 + qs*128 + wave*32 + lr5)*D_MODEL + dc*16 + hi*8];

    // ones B-fragment for the rank-1 mask update: B[q][k]=1 at k=0 only
    u32x4 onew = {};
    onew[0] = hi ? 0u : 0x3F80u;
    const bf16x8 qone = __builtin_bit_cast(bf16x8, onew);

    // ---- stage bf16 mask bias row once (all 256 threads, 8 keys each)
    {
        const int4* mp = (const int4*)&mask[(size_t)b*SEQ + tid*8];
        int4 m0 = mp[0], m1 = mp[1];
        bf16x8 mm;
        mm[0] = (m0.x == 0) ? (bf16_t)(-1e30f) : (bf16_t)0.0f;
        mm[1] = (m0.y == 0) ? (bf16_t)(-1e30f) : (bf16_t)0.0f;
        mm[2] = (m0.z == 0) ? (bf16_t)(-1e30f) : (bf16_t)0.0f;
        mm[3] = (m0.w == 0) ? (bf16_t)(-1e30f) : (bf16_t)0.0f;
        mm[4] = (m1.x == 0) ? (bf16_t)(-1e30f) : (bf16_t)0.0f;
        mm[5] = (m1.y == 0) ? (bf16_t)(-1e30f) : (bf16_t)0.0f;
        mm[6] = (m1.z == 0) ? (bf16_t)(-1e30f) : (bf16_t)0.0f;
        mm[7] = (m1.w == 0) ? (bf16_t)(-1e30f) : (bf16_t)0.0f;
        *(bf16x8*)&mbias[tid*8] = mm;
    }

    auto stage = [&](int t, int buf) {
#pragma unroll
        for (int p = 0; p < 2; ++p) {
            int chunk = p*256 + tid; int r = chunk >> 3;
            int cs = ((chunk & 7) ^ (r & 7)) * 8;
            gload16(Kp + base + (size_t)(t*64 + r)*D_MODEL + cs,
                    (bf16_t*)Ks[buf] + (size_t)chunk*8);
            gload16(Vt + vbase + (size_t)r*SEQ + t*64 + cs,
                    (bf16_t*)Vs[buf] + (size_t)chunk*8);
        }
    };

    f32x16 oA0 = {}, oA1 = {};        // q-sub 0: O^T accumulators (d 0..31 / 32..63)
    f32x16 oB0 = {}, oB1 = {};        // q-sub 1
    float lA = 0.f, lB = 0.f;         // own-half softmax denominators

    // ---- prologue: issue tiles 0,1,2; counted wait (qf+mask+tile0 retired)
    stage(0, 0); stage(1, 1); stage(2, 2);
    asm volatile("s_waitcnt vmcnt(8) lgkmcnt(0)");
    __builtin_amdgcn_s_barrier();

    int cb = 0;                        // current buffer = t % 3
    for (int t = 0; t < SEQ/64; ++t) {
        // ---- mask A-fragments (shared by both q-subs)
        u32 mw0 = (u32)__builtin_bit_cast(unsigned short, mbias[t*64 + lr5]);
        u32 mw1 = (u32)__builtin_bit_cast(unsigned short, mbias[t*64 + 32 + lr5]);
        if (hi) { mw0 = 0; mw1 = 0; }
        u32x4 mv0 = {}, mv1 = {};
        mv0[0] = mw0; mv1[0] = mw1;
        bf16x8 afm0 = __builtin_bit_cast(bf16x8, mv0);
        bf16x8 afm1 = __builtin_bit_cast(bf16x8, mv1);

        const char* KsB = (const char*)Ks[cb];
        const char* VsB = (const char*)Vs[cb];

#pragma unroll
        for (int qs = 0; qs < 2; ++qs) {
            // ---- QK(t,qs): S^T[key][q], accumulator initialized with rank-1 mask
            const f32x16 zz = {};
            f32x16 s0, s1;
            __builtin_amdgcn_s_setprio(1);
            s0 = __builtin_amdgcn_mfma_f32_32x32x16_bf16(afm0, qone, zz, 0, 0, 0);
            s1 = __builtin_amdgcn_mfma_f32_32x32x16_bf16(afm1, qone, zz, 0, 0, 0);
#pragma unroll
            for (int dc = 0; dc < 4; ++dc) {
                int colb = dc*32 + hi*16;
                int row0 = lr5, row1 = 32 + lr5;
                bf16x8 kf0 = *(const bf16x8*)(KsB + ((row0*128 + colb) ^ ((row0 & 7) << 4)));
                bf16x8 kf1 = *(const bf16x8*)(KsB + ((row1*128 + colb) ^ ((row1 & 7) << 4)));
                s0 = __builtin_amdgcn_mfma_f32_32x32x16_bf16(kf0, qf[qs][dc], s0, 0, 0, 0);
                s1 = __builtin_amdgcn_mfma_f32_32x32x16_bf16(kf1, qf[qs][dc], s1, 0, 0, 0);
            }
            __builtin_amdgcn_s_setprio(0);

            // ---- per kt-half: exp2 -> sum -> pack -> PV (pv[16] live at a time)
            float lsum = 0.f;
#pragma unroll
            for (int kt = 0; kt < 2; ++kt) {
                const f32x16& sh = kt ? s1 : s0;
                float pv[16];
#pragma unroll
                for (int r = 0; r < 16; ++r) pv[r] = __builtin_exp2f(sh[r]);
                float su0 = 0.f, su1 = 0.f, su2 = 0.f, su3 = 0.f;
#pragma unroll
                for (int r = 0; r < 16; r += 4) {
                    su0 += pv[r]; su1 += pv[r+1]; su2 += pv[r+2]; su3 += pv[r+3];
                }
                lsum += (su0 + su1) + (su2 + su3);
#pragma unroll
                for (int c = 0; c < 2; ++c) {
                    u32x4 fwv;
#pragma unroll
                    for (int i = 0; i < 4; ++i)
                        fwv[i] = pk2(pv[c*8 + 2*i], pv[c*8 + 2*i + 1]);
                    bf16x8 pfrag = __builtin_bit_cast(bf16x8, fwv);
                    int colb = kt*64 + c*32 + hi*16;
                    int row0 = lr5, row1 = 32 + lr5;
                    bf16x8 vf0 = *(const bf16x8*)(VsB + ((row0*128 + colb) ^ ((row0 & 7) << 4)));
                    bf16x8 vf1 = *(const bf16x8*)(VsB + ((row1*128 + colb) ^ ((row1 & 7) << 4)));
                    __builtin_amdgcn_s_setprio(1);
                    if (qs == 0) {
                        oA0 = __builtin_amdgcn_mfma_f32_32x32x16_bf16(vf0, pfrag, oA0, 0, 0, 0);
                        oA1 = __builtin_amdgcn_mfma_f32_32x32x16_bf16(vf1, pfrag, oA1, 0, 0, 0);
                    } else {
                        oB0 = __builtin_amdgcn_mfma_f32_32x32x16_bf16(vf0, pfrag, oB0, 0, 0, 0);
                        oB1 = __builtin_amdgcn_mfma_f32_32x32x16_bf16(vf1, pfrag, oB1, 0, 0, 0);
                    }
                    __builtin_amdgcn_s_setprio(0);
                }
            }
            if (qs == 0) lA += lsum; else lB += lsum;
        }

        // ---- boundary: counted wait — stage(t+1) retired, stage(t+2) stays in flight
        asm volatile("s_waitcnt vmcnt(4) lgkmcnt(0)");
        __builtin_amdgcn_s_barrier();
        if (t + 3 < SEQ/64) stage(t + 3, cb);   // buffer (t+3)%3 == t%3 == cb
        ++cb; if (cb == 3) cb = 0;
    }

    // ---- epilogue per q-sub: cross-half l; O^T/l; transpose through LDS; store
    char* TrB = (char*)Ks;            // 16KB reuse (final barrier above protects)
    const int qloc = wave*32 + lr5;
#pragma unroll
    for (int qs = 0; qs < 2; ++qs) {
        if (qs) __syncthreads();      // protect TrB reuse between q-subs
        float lr_ = (qs == 0) ? lA : lB;
        float l_tot = lr_ + __shfl_xor(lr_, 32);
        float inv = 1.f / l_tot;
#pragma unroll
        for (int mt = 0; mt < 2; ++mt)
#pragma unroll
            for (int r = 0; r < 16; ++r) {
                int d = mt*32 + (r & 3) + 8*(r >> 2) + 4*hi;
                float val = (qs == 0 ? (mt ? oA1[r] : oA0[r])
                                     : (mt ? oB1[r] : oB0[r])) * inv;
                *(bf16_t*)(TrB + (qloc*128 + ((d*2) ^ ((qloc & 7) << 4)))) = (bf16_t)val;
            }
        __syncthreads();
#pragma unroll
        for (int p = 0; p < 4; ++p) {
            int id = p*256 + tid;
            int row = id >> 3, g = id & 7;
            bf16x8 v8 = *(const bf16x8*)(TrB + (row*128 + ((g*16) ^ ((row & 7) << 4))));
            *(bf16x8*)&AO[base + (size_t)(q0 + qs*128 + row)*D_MODEL + g*8] = v8;
        }
    }
}

extern "C" void kernel_launch(void* const* d_in, const int* in_sizes, int n_in,
                              void* d_out, int out_size, void* d_ws, size_t ws_size,
                              hipStream_t stream) {
    (void)in_sizes; (void)n_in; (void)out_size; (void)ws_size;
    const float* q    = (const float*)d_in[0];
    const float* k    = (const float*)d_in[1];
    const float* v    = (const float*)d_in[2];
    const int*   mask = (const int*)d_in[3];
    const float* wq_w = (const float*)d_in[4];
    const float* wq_b = (const float*)d_in[5];
    const float* wk_w = (const float*)d_in[6];
    const float* wk_b = (const float*)d_in[7];
    const float* wv_w = (const float*)d_in[8];
    const float* wv_b = (const float*)d_in[9];
    const float* wo_w = (const float*)d_in[10];
    const float* wo_b = (const float*)d_in[11];
    float* out = (float*)d_out;

    const size_t ACT = (size_t)MROWS * D_MODEL;
    const size_t WSZ = (size_t)D_MODEL * D_MODEL;
    // Rotating buffers: B0=q_bf16->Kp, B1=k_bf16->Vt, B2=v_bf16->AO, B3=Qp
    bf16_t* B0 = (bf16_t*)d_ws;
    bf16_t* B1 = B0 + ACT;
    bf16_t* B2 = B1 + ACT;
    bf16_t* B3 = B2 + ACT;
    bf16_t* Wq = B3 + ACT;
    bf16_t* Wk = Wq + WSZ;
    bf16_t* Wv = Wk + WSZ;
    bf16_t* Wo = Wv + WSZ;

    const int wn8 = (int)(WSZ/8), an8 = (int)(ACT/8);
    cvtw_kernel<<<dim3(wn8/256, 4), dim3(256), 0, stream>>>(wq_w, Wq, wk_w, Wk, wv_w, Wv, wo_w, Wo, wn8);
    cvt3_kernel<<<dim3(an8/256, 3), dim3(256), 0, stream>>>(q, B0, k, B1, v, B2, an8);

    const int ggrid = (MROWS/128) * (D_MODEL/128);   // 512, 1-D XCD-aligned
    gemm_bt<1><<<ggrid, dim3(256), 0, stream>>>(B0, Wq, wq_b, B3, nullptr, MROWS, D_MODEL, D_MODEL, SC);
    gemm_bt<1><<<ggrid, dim3(256), 0, stream>>>(B1, Wk, wk_b, B0, nullptr, MROWS, D_MODEL, D_MODEL, 1.f);
    gemm_bt<2><<<ggrid, dim3(256), 0, stream>>>(B2, Wv, wv_b, B1, nullptr, MROWS, D_MODEL, D_MODEL, 1.f);

    attn_kernel<<<dim3(SEQ/256, NHEAD, BATCH), dim3(256), 0, stream>>>(B3, B0, B1, mask, B2);

    gemm_bt<0><<<ggrid, dim3(256), 0, stream>>>(B2, Wo, wo_b, nullptr, out, MROWS, D_MODEL, D_MODEL, 1.f);
}